// Round 1
// baseline (91.331 us; speedup 1.0000x reference)
//
#include <hip/hip_runtime.h>

// R9: full fusion. The R8 split spent ~40us in EACH kernel while the roofline
// floor for the pair is ~12us — the cost was the q/k/v workspace round-trip
// (14MB scattered f16 stores + 33MB reloads + a kernel boundary), not compute.
// This kernel computes q,k,v per 8x8 tile with per-wave MFMAs reading x
// DIRECTLY from global (kernel-A fragment convention: 16 consecutive px x 4
// ch-rows per load instr, coalesced), and writes D straight into the
// interleaved kvb LDS buffer (k and v for one (px,ch) live in the same lane,
// so the k|v<<16 pack is in-register) + a small f32 qbuf. Row reflection is
// folded into the A-frag address; column reflection is the R6 kvb fixup.
// Phase 3 (25-tap softmax) is R6/R8 verbatim.
//  - no d_ws usage at all; traffic = x (L3-warm halo re-reads) + out only
//  - LDS 39.7 KB -> 4 blocks/CU, 16 waves/CU; 1 barrier interior, 2 edge

#define HW 96
#define RG 12
#define CSTR 36            // dwords per position in kvb (32 ch + 4 pad)
#define QSTR 33            // floats per position in qbuf (32 ch + 1 pad)
#define PXN 9216           // 96*96

typedef _Float16 half8  __attribute__((ext_vector_type(8)));
typedef _Float16 half2v __attribute__((ext_vector_type(2)));
typedef float    float4v __attribute__((ext_vector_type(4)));
typedef unsigned int uint4v __attribute__((ext_vector_type(4)));

__device__ __forceinline__ int refl(int i) {
    i = (i < 0) ? -i : i;          // reflect (edge excluded): -1->1, -2->2
    i = (i > 95) ? (190 - i) : i;  // 96->94, 97->93
    return i;
}

// grid (144, 4, 2): one block per 8x8 output tile per (g,b).
__global__ __launch_bounds__(256) void fused_attn(
    const float* __restrict__ x, const float* __restrict__ wq,
    const float* __restrict__ wk, const float* __restrict__ wv,
    float* __restrict__ out)
{
    __shared__ unsigned int kvb[144 * CSTR];   // k|v<<16 per (pos,ch), 20736 B
    __shared__ float qbuf[144 * QSTR];         // q f32 per (pos,ch),   19008 B

    const int tid = threadIdx.x;
    const int g = blockIdx.y, b = blockIdx.z;
    const int h0 = (blockIdx.x / 12) * 8;
    const int w0 = (blockIdx.x % 12) * 8;
    const int lane = tid & 63, wid = tid >> 6;
    const int col = lane & 15, quad = lane >> 4, koff = quad * 8;
    const int ty = lane >> 3, tx = lane & 7, n0 = wid * 8;

    const int wA  = min(max(w0 - 4, 0), 80);   // 16-px aligned staging window
    const int off = w0 - 2 - wA;               // lds col s = px_i - off

    const float* xg = x + (size_t)(b * 128 + g * 32) * PXN;

    // ---- B-fragments (weights): T = type*2+half; q pre-scaled by log2e ----
    const float* wsrc[3] = {wq, wk, wv};
    half8 frag[6];
    #pragma unroll
    for (int T = 0; T < 6; T++) {
        const float* wr = wsrc[T >> 1] + (g * 32 + (T & 1) * 16 + col) * 32 + koff;
        float4v lo = *(const float4v*)(wr);
        float4v hi = *(const float4v*)(wr + 4);
        float sc = (T < 2) ? 1.44269504f : 1.0f;
        #pragma unroll
        for (int j = 0; j < 4; j++) {
            frag[T][j]     = (_Float16)(lo[j] * sc);
            frag[T][j + 4] = (_Float16)(hi[j] * sc);
        }
    }

    // ---- A-fragments: 3 halo rows per wave, straight from global x.
    // Per load instr: 16 consecutive floats x 4 ch-rows = 4x64B segments.
    float av[3][8];
    #pragma unroll
    for (int t = 0; t < 3; t++) {
        int iy = refl(h0 + (wid * 3 + t) - 2);
        const float* xr = xg + (size_t)iy * HW + wA + col;
        #pragma unroll
        for (int j = 0; j < 8; j++)
            av[t][j] = xr[(size_t)(koff + j) * PXN];
    }

    // ---- conv phase: 6 MFMAs per row-tile, D written direct to LDS.
    // D layout: lane holds D[px = quad*4+r][cout = col]; same lane holds the
    // matching k and v element -> pack k|v<<16 in-register (RNE casts).
    #pragma unroll
    for (int t = 0; t < 3; t++) {
        const int row = wid * 3 + t;
        half8 a;
        #pragma unroll
        for (int j = 0; j < 8; j++) a[j] = (_Float16)av[t][j];
        #pragma unroll
        for (int hf = 0; hf < 2; hf++) {
            float4v z = {0.f, 0.f, 0.f, 0.f};
            float4v dq = __builtin_amdgcn_mfma_f32_16x16x32_f16(a, frag[hf],     z, 0, 0, 0);
            float4v dk = __builtin_amdgcn_mfma_f32_16x16x32_f16(a, frag[2 + hf], z, 0, 0, 0);
            float4v dv = __builtin_amdgcn_mfma_f32_16x16x32_f16(a, frag[4 + hf], z, 0, 0, 0);
            const int ch = hf * 16 + col;
            #pragma unroll
            for (int r = 0; r < 4; r++) {
                int s = quad * 4 + r - off;    // window px -> lds col
                if (s >= 0 && s < RG) {
                    int p = row * RG + s;
                    half2v kv;
                    kv[0] = (_Float16)dk[r];
                    kv[1] = (_Float16)dv[r];
                    kvb[p * CSTR + ch]  = __builtin_bit_cast(unsigned int, kv);
                    qbuf[p * QSTR + ch] = dq[r];
                }
            }
        }
    }
    __syncthreads();

    // ---- reflect fixup for edge columns (block-uniform branch) ----
    // Interior q pixels (s=tx+2, row=ty+2) are never reflected: kvb only.
    if (off != 2) {
        const int left = (w0 == 0);
        #pragma unroll
        for (int it = 0; it < 3; it++) {
            int idx = it * 256 + tid;          // 768 = 12 rows x 2 cols x 32 ch
            int ch = idx & 31, rr = idx >> 5;
            int row = rr >> 1, wc = rr & 1;
            int dst = left ? wc : (10 + wc);
            int src = left ? (4 - wc) : (8 - wc);
            kvb[(row * RG + dst) * CSTR + ch] = kvb[(row * RG + src) * CSTR + ch];
        }
        __syncthreads();
    }

    // ---- phase 3: 25-tap softmax, 8 channels; lane = pixel (R6 verbatim) ----
    float qf[8];
    {
        const float* qb = &qbuf[((ty + 2) * RG + (tx + 2)) * QSTR + n0];
        #pragma unroll
        for (int c = 0; c < 8; c++) qf[c] = qb[c];   // pre-scaled by log2e
    }

    float den[8], num[8];
    #pragma unroll
    for (int c = 0; c < 8; c++) { den[c] = 0.f; num[c] = 0.f; }

    #pragma unroll
    for (int dy = 0; dy < 5; dy++) {
        const unsigned int* base = &kvb[((ty + dy) * RG + tx) * CSTR + n0];
        uint4v t0[5], t1[5];
        #pragma unroll
        for (int dx = 0; dx < 5; dx++) {            // 10 ds_read_b128 batched
            t0[dx] = *(const uint4v*)(base + dx * CSTR);
            t1[dx] = *(const uint4v*)(base + dx * CSTR + 4);
        }
        #pragma unroll
        for (int dx = 0; dx < 5; dx++) {
            #pragma unroll
            for (int c = 0; c < 8; c++) {
                unsigned int u = (c < 4) ? t0[dx][c] : t1[dx][c - 4];
                half2v kv = __builtin_bit_cast(half2v, u);
                float e = __builtin_amdgcn_exp2f(qf[c] * (float)kv[0]);
                den[c] += e;
                num[c] = fmaf(e, (float)kv[1], num[c]);
            }
        }
    }

    float* outp = out + (size_t)((b * 128 + g * 32 + n0) * HW + (h0 + ty)) * HW + (w0 + tx);
    #pragma unroll
    for (int c = 0; c < 8; c++)
        outp[c * (HW * HW)] = num[c] * __builtin_amdgcn_rcpf(den[c]);
}

extern "C" void kernel_launch(void* const* d_in, const int* in_sizes, int n_in,
                              void* d_out, int out_size, void* d_ws, size_t ws_size,
                              hipStream_t stream) {
    const float* x  = (const float*)d_in[0];
    const float* wq = (const float*)d_in[1];
    const float* wk = (const float*)d_in[2];
    const float* wv = (const float*)d_in[3];
    float* out = (float*)d_out;
    (void)d_ws; (void)ws_size;

    fused_attn<<<dim3(144, 4, 2), 256, 0, stream>>>(x, wq, wk, wv, out);
}